// Round 9
// baseline (263.058 us; speedup 1.0000x reference)
//
#include <hip/hip_runtime.h>
#include <math.h>

constexpr int S_  = 2048;
constexpr int D_  = 1024;
constexpr int H_  = 16;
constexpr int HD_ = 64;
constexpr int FF_ = 4096;

typedef short bf16x8 __attribute__((ext_vector_type(8)));
typedef float f32x4  __attribute__((ext_vector_type(4)));

// HW bf16 convert (RNE), same numerics as manual round-to-nearest-even.
static __device__ __forceinline__ ushort f2bf(float f) {
    union { __bf16 b; ushort u; } c;
    c.b = (__bf16)f;
    return c.u;
}
static __device__ __forceinline__ float bf2f(ushort u) {
    return __uint_as_float(((unsigned)u) << 16);
}

// exp(x/8) = 2^(x * 0.125*log2(e)) — one v_mul + v_exp_f32
static __device__ __forceinline__ float exp8(float x) {
    return __builtin_amdgcn_exp2f(x * 0.18033688f);
}

// async global -> LDS, 16 bytes per lane (global_load_lds_dwordx4).
// LDS dest semantics: wave-uniform base + lane*16; per-lane SOURCE address
// is free — we put the XOR bank swizzle there.
static __device__ __forceinline__ void gload_lds16(const void* g, void* l) {
    __builtin_amdgcn_global_load_lds(
        (const __attribute__((address_space(1))) unsigned int*)g,
        (__attribute__((address_space(3))) unsigned int*)l, 16, 0, 0);
}

// ---------------------------------------------------------------------------
// 32n x 128k transpose+cast tile (block-level, 256 threads).
// out[n][k] (bf16, row stride K) = in[k][n] (fp32, row stride N).
// Each n-row is written as 256 B contiguous (2x uint4 per thread).
// ---------------------------------------------------------------------------
static __device__ __forceinline__ void tc_tile128(
    const float* __restrict__ in, ushort* __restrict__ out,
    int K, int N, int n0, int k0)
{
    __shared__ float Ts[32][132];   // [n][k-local], +4 pad
    const int tid = threadIdx.x;
    const int kr = tid >> 3;          // 0..31
    const int nc = (tid & 7) * 4;     // 0..28
#pragma unroll
    for (int p = 0; p < 4; ++p) {
        const int kk = p * 32 + kr;
        float4 v = *(const float4*)(in + (size_t)(k0 + kk) * N + n0 + nc);
        Ts[nc + 0][kk] = v.x; Ts[nc + 1][kk] = v.y;
        Ts[nc + 2][kk] = v.z; Ts[nc + 3][kk] = v.w;
    }
    __syncthreads();
    const int r = tid >> 3;           // n-row 0..31
    const int c16 = (tid & 7) * 16;   // k base (16 elems per thread)
    union { uint4 u; ushort s[8]; } pk;
#pragma unroll
    for (int hh = 0; hh < 2; ++hh) {
#pragma unroll
        for (int j = 0; j < 8; ++j)
            pk.s[j] = f2bf(Ts[r][c16 + hh * 8 + j]);
        *(uint4*)(out + (size_t)(n0 + r) * K + k0 + c16 + hh * 8) = pk.u;
    }
}

// ---------------------------------------------------------------------------
// One fused pack kernel: x cast + 6 weight transposes + bias concat.
// Grid: [0,2048) xcast | [2048,2816) Wqkv | [2816,3072) Wp |
//       [3072,4096) W1 | [4096,5120) W2 | [5120,5132) bias
// ---------------------------------------------------------------------------
__global__ __launch_bounds__(256) void pack_all(
    const float* __restrict__ x,
    const float* __restrict__ Wq, const float* __restrict__ Wk,
    const float* __restrict__ Wv, const float* __restrict__ Wp,
    const float* __restrict__ W1, const float* __restrict__ W2,
    const float* __restrict__ bq, const float* __restrict__ bk,
    const float* __restrict__ bv,
    ushort* __restrict__ xb, ushort* __restrict__ BTqkv,
    ushort* __restrict__ BTp, ushort* __restrict__ BT1,
    ushort* __restrict__ BT2, float* __restrict__ biascat)
{
    const int b = blockIdx.x;
    const int tid = threadIdx.x;
    if (b < 2048) {                       // cast x -> bf16
        const int i = b * 1024 + tid * 4;
        float4 v = *(const float4*)(x + i);
        ushort4 o;
        o.x = f2bf(v.x); o.y = f2bf(v.y); o.z = f2bf(v.z); o.w = f2bf(v.w);
        *(ushort4*)(xb + i) = o;
    } else if (b < 2816) {                // Wq/Wk/Wv [H][1024][64] -> BT
        int j = b - 2048;                 // 768 = 3 * 16 heads * 16 tiles
        const int which = j >> 8;         // 0=q 1=k 2=v
        j &= 255;
        const int hh = j >> 4, t = j & 15;
        const float* W = (which == 0) ? Wq : (which == 1) ? Wk : Wv;
        tc_tile128(W + hh * 65536, BTqkv + which * 1024 * 1024 + hh * 65536,
                   1024, 64, (t & 1) * 32, (t >> 1) * 128);
    } else if (b < 3072) {                // Wp [1024][1024] (256 tiles)
        const int j = b - 2816;
        tc_tile128(Wp, BTp, 1024, 1024, (j & 31) * 32, (j >> 5) * 128);
    } else if (b < 4096) {                // W1 [1024][4096] (1024 tiles)
        const int j = b - 3072;
        tc_tile128(W1, BT1, 1024, 4096, (j & 127) * 32, (j >> 7) * 128);
    } else if (b < 5120) {                // W2 [4096][1024] (1024 tiles)
        const int j = b - 4096;
        tc_tile128(W2, BT2, 4096, 1024, (j & 31) * 32, (j >> 5) * 128);
    } else {                              // bias concat
        const int i = (b - 5120) * 256 + tid;
        float v = (i < 1024) ? bq[i] : (i < 2048 ? bk[i - 1024] : bv[i - 2048]);
        biascat[i] = v;
    }
}

// ---------------------------------------------------------------------------
// m97-style bf16 MFMA GEMM, BK=64, global_load_lds staging with source-side
// XOR swizzle. OUT: 0=f32+bias, 1=bf16+bias, 2=f32 split-K partials (dual),
// 3=QKV special (QKcat bf16 + V^T bf16), 4=bf16 split-K partials (single Cv).
// ---------------------------------------------------------------------------
template <int BM, int BN, int WR, int WC, int KS, int RELU, int OUT>
__global__ __launch_bounds__(WR * WC * 64) void gemm_mfma(
    const ushort* __restrict__ A, const ushort* __restrict__ BT,
    const float* __restrict__ bias, void* __restrict__ Cv,
    void* __restrict__ Cv2, int M, int N, int K)
{
    constexpr int WAVES = WR * WC;
    constexpr int WTM = BM / WR, WTN = BN / WC;
    constexpr int MT = WTM / 16, NT = WTN / 16;
    constexpr int AI = BM / 8;
    constexpr int TI = (BM + BN) / 8;
    constexpr int PW = TI / WAVES;

    __shared__ ushort As[BM * 64];
    __shared__ ushort Bs[BN * 64];

    const int tid = threadIdx.x;
    const int lane = tid & 63;
    const int wave = tid >> 6;
    const int wr = wave / WC, wc = wave % WC;
    const int row16 = lane & 15, kgrp = lane >> 4;
    const int m0 = blockIdx.y * BM, n0 = blockIdx.x * BN;
    const int kOff = (KS > 1) ? blockIdx.z * (K / KS) : 0;

    const int lrow = lane >> 3;
    const int sc8 = (lane & 7) ^ lrow;

    f32x4 acc[MT][NT];
#pragma unroll
    for (int i = 0; i < MT; ++i)
#pragma unroll
        for (int j = 0; j < NT; ++j) acc[i][j] = (f32x4){0.f, 0.f, 0.f, 0.f};

    for (int k0 = kOff; k0 < kOff + K / KS; k0 += 64) {
        __syncthreads();
#pragma unroll
        for (int i = 0; i < PW; ++i) {
            const int inst = wave * PW + i;
            if (inst < AI) {
                const int row = inst * 8;
                gload_lds16(A + (size_t)(m0 + row + lrow) * K + k0 + sc8 * 8,
                            As + row * 64);
            } else {
                const int row = (inst - AI) * 8;
                gload_lds16(BT + (size_t)(n0 + row + lrow) * K + k0 + sc8 * 8,
                            Bs + row * 64);
            }
        }
        __syncthreads();
#pragma unroll
        for (int ks = 0; ks < 2; ++ks) {
            bf16x8 af[MT], bfr[NT];
#pragma unroll
            for (int mt = 0; mt < MT; ++mt) {
                const int r = wr * WTM + mt * 16 + row16;
                af[mt] = *(const bf16x8*)(As + r * 64 + (((ks * 4 + kgrp) ^ (r & 7)) * 8));
            }
#pragma unroll
            for (int nt = 0; nt < NT; ++nt) {
                const int r = wc * WTN + nt * 16 + row16;
                bfr[nt] = *(const bf16x8*)(Bs + r * 64 + (((ks * 4 + kgrp) ^ (r & 7)) * 8));
            }
#pragma unroll
            for (int mt = 0; mt < MT; ++mt)
#pragma unroll
                for (int nt = 0; nt < NT; ++nt)
                    acc[mt][nt] = __builtin_amdgcn_mfma_f32_16x16x32_bf16(
                        af[mt], bfr[nt], acc[mt][nt], 0, 0, 0);
        }
    }

    if constexpr (OUT == 2) {
        float* Cp = ((blockIdx.z < KS / 2) ? (float*)Cv : (float*)Cv2)
                    + (size_t)(blockIdx.z % (KS / 2)) * M * N;
#pragma unroll
        for (int nt = 0; nt < NT; ++nt) {
            const int n = n0 + wc * WTN + nt * 16 + row16;
#pragma unroll
            for (int mt = 0; mt < MT; ++mt)
#pragma unroll
                for (int r = 0; r < 4; ++r) {
                    const int m = m0 + wr * WTM + mt * 16 + kgrp * 4 + r;
                    Cp[(size_t)m * N + n] = acc[mt][nt][r];
                }
        }
    } else if constexpr (OUT == 4) {
        ushort* Cp = (ushort*)Cv + (size_t)blockIdx.z * M * N;
#pragma unroll
        for (int nt = 0; nt < NT; ++nt) {
            const int n = n0 + wc * WTN + nt * 16 + row16;
#pragma unroll
            for (int mt = 0; mt < MT; ++mt)
#pragma unroll
                for (int r = 0; r < 4; ++r) {
                    const int m = m0 + wr * WTM + mt * 16 + kgrp * 4 + r;
                    Cp[(size_t)m * N + n] = f2bf(acc[mt][nt][r]);
                }
        }
    } else if constexpr (OUT == 3) {
        ushort* QKo = (ushort*)Cv;
        ushort* VTo = (ushort*)Cv2;
        if (n0 < 2048) {
#pragma unroll
            for (int nt = 0; nt < NT; ++nt) {
                const int n = n0 + wc * WTN + nt * 16 + row16;
                const float bb = bias[n];
#pragma unroll
                for (int mt = 0; mt < MT; ++mt)
#pragma unroll
                    for (int r = 0; r < 4; ++r) {
                        const int m = m0 + wr * WTM + mt * 16 + kgrp * 4 + r;
                        QKo[(size_t)m * 2048 + n] = f2bf(acc[mt][nt][r] + bb);
                    }
            }
        } else {
#pragma unroll
            for (int nt = 0; nt < NT; ++nt) {
                const int n = n0 + wc * WTN + nt * 16 + row16;
                const float bb = bias[n];
#pragma unroll
                for (int mt = 0; mt < MT; ++mt) {
                    const int mb = m0 + wr * WTM + mt * 16 + kgrp * 4;
                    ushort4 o;
                    o.x = f2bf(acc[mt][nt][0] + bb);
                    o.y = f2bf(acc[mt][nt][1] + bb);
                    o.z = f2bf(acc[mt][nt][2] + bb);
                    o.w = f2bf(acc[mt][nt][3] + bb);
                    *(ushort4*)(VTo + (size_t)(n - 2048) * 2048 + mb) = o;
                }
            }
        }
    } else {
#pragma unroll
        for (int nt = 0; nt < NT; ++nt) {
            const int n = n0 + wc * WTN + nt * 16 + row16;
            const float bb = bias ? bias[n] : 0.f;
#pragma unroll
            for (int mt = 0; mt < MT; ++mt)
#pragma unroll
                for (int r = 0; r < 4; ++r) {
                    const int m = m0 + wr * WTM + mt * 16 + kgrp * 4 + r;
                    float v = acc[mt][nt][r] + bb;
                    if (RELU) v = fmaxf(v, 0.f);
                    if (OUT == 1)
                        ((ushort*)Cv)[(size_t)m * N + n] = f2bf(v);
                    else
                        ((float*)Cv)[(size_t)m * N + n] = v;
                }
        }
    }
}

// out[i] = sum of 4 bf16 split-K partials + bias  (FF2, fp32 out)
__global__ __launch_bounds__(256) void reduce4_bias_b(
    const ushort* __restrict__ p, const float* __restrict__ bias,
    float* __restrict__ out, int MN, int N)
{
    const int i = (blockIdx.x * 256 + threadIdx.x) * 8;
    union { uint4 u; ushort s[8]; } a, b, c, d;
    a.u = *(const uint4*)(p + i);
    b.u = *(const uint4*)(p + (size_t)MN + i);
    c.u = *(const uint4*)(p + 2 * (size_t)MN + i);
    d.u = *(const uint4*)(p + 3 * (size_t)MN + i);
    const float4 e0 = *(const float4*)(bias + (i & (N - 1)));
    const float4 e1 = *(const float4*)(bias + ((i + 4) & (N - 1)));
    float4 o0, o1;
    o0.x = bf2f(a.s[0]) + bf2f(b.s[0]) + bf2f(c.s[0]) + bf2f(d.s[0]) + e0.x;
    o0.y = bf2f(a.s[1]) + bf2f(b.s[1]) + bf2f(c.s[1]) + bf2f(d.s[1]) + e0.y;
    o0.z = bf2f(a.s[2]) + bf2f(b.s[2]) + bf2f(c.s[2]) + bf2f(d.s[2]) + e0.z;
    o0.w = bf2f(a.s[3]) + bf2f(b.s[3]) + bf2f(c.s[3]) + bf2f(d.s[3]) + e0.w;
    o1.x = bf2f(a.s[4]) + bf2f(b.s[4]) + bf2f(c.s[4]) + bf2f(d.s[4]) + e1.x;
    o1.y = bf2f(a.s[5]) + bf2f(b.s[5]) + bf2f(c.s[5]) + bf2f(d.s[5]) + e1.y;
    o1.z = bf2f(a.s[6]) + bf2f(b.s[6]) + bf2f(c.s[6]) + bf2f(d.s[6]) + e1.z;
    o1.w = bf2f(a.s[7]) + bf2f(b.s[7]) + bf2f(c.s[7]) + bf2f(d.s[7]) + e1.w;
    *(float4*)(out + i) = o0;
    *(float4*)(out + i + 4) = o1;
}

// ---------------------------------------------------------------------------
// attn_stats: part[tz][h][s] = sum_{t in tz half} exp(Q[s].K[t]/8)
// t-split x2; 1 barrier/iter; double-buffered K staging.
// ---------------------------------------------------------------------------
__global__ __launch_bounds__(256) void attn_stats(
    const ushort* __restrict__ QK, float* __restrict__ part)
{
    const int h = blockIdx.y;
    const int s0 = blockIdx.x * 128;
    const int tz = blockIdx.z;
    const int tid = threadIdx.x;
    const int lane = tid & 63;
    const int w = tid >> 6;
    const int row16 = lane & 15;
    const int kgrp = lane >> 4;

    __shared__ ushort Ks[2][64 * 64];

    bf16x8 qf[2][2];
#pragma unroll
    for (int mt = 0; mt < 2; ++mt) {
        const ushort* qp = QK + (size_t)(s0 + w * 32 + mt * 16 + row16) * 2048 + h * 64;
        qf[mt][0] = *(const bf16x8*)(qp + kgrp * 8);
        qf[mt][1] = *(const bf16x8*)(qp + kgrp * 8 + 32);
    }

    float suml[2][4] = {{0.f}};
    const int lr = lane >> 3;                 // row within 8-row inst
    const int sw8 = ((lane & 7) ^ lr) * 8;    // swizzled source chunk

    // prologue: stage ti=0 into buf 0
#pragma unroll
    for (int i = 0; i < 2; ++i) {
        const int inst = w * 2 + i;
        gload_lds16(QK + (size_t)(tz * 1024 + inst * 8 + lr) * 2048 + 1024 + h * 64 + sw8,
                    Ks[0] + inst * 512);
    }

    for (int ti = 0; ti < 16; ++ti) {
        __syncthreads();                      // drains DMA(ti); compute(ti-1) done
        if (ti < 15) {
            const int t1 = tz * 1024 + (ti + 1) * 64;
            ushort* kb = Ks[(ti + 1) & 1];
#pragma unroll
            for (int i = 0; i < 2; ++i) {
                const int inst = w * 2 + i;
                gload_lds16(QK + (size_t)(t1 + inst * 8 + lr) * 2048 + 1024 + h * 64 + sw8,
                            kb + inst * 512);
            }
        }
        const ushort* Kb = Ks[ti & 1];
#pragma unroll
        for (int nt = 0; nt < 4; ++nt) {
            const int kr = nt * 16 + row16;
            bf16x8 kf0 = *(const bf16x8*)(Kb + kr * 64 + ((kgrp ^ (kr & 7)) * 8));
            bf16x8 kf1 = *(const bf16x8*)(Kb + kr * 64 + (((kgrp + 4) ^ (kr & 7)) * 8));
#pragma unroll
            for (int mt = 0; mt < 2; ++mt) {
                f32x4 sc = (f32x4){0.f, 0.f, 0.f, 0.f};
                sc = __builtin_amdgcn_mfma_f32_16x16x32_bf16(qf[mt][0], kf0, sc, 0, 0, 0);
                sc = __builtin_amdgcn_mfma_f32_16x16x32_bf16(qf[mt][1], kf1, sc, 0, 0, 0);
#pragma unroll
                for (int r = 0; r < 4; ++r)
                    suml[mt][r] += exp8(sc[r]);
            }
        }
    }
#pragma unroll
    for (int mt = 0; mt < 2; ++mt)
#pragma unroll
        for (int r = 0; r < 4; ++r) {
#pragma unroll
            for (int m = 1; m < 16; m <<= 1)
                suml[mt][r] += __shfl_xor(suml[mt][r], m, 64);
        }
    if (row16 == 0) {
#pragma unroll
        for (int mt = 0; mt < 2; ++mt)
#pragma unroll
            for (int r = 0; r < 4; ++r)
                part[((size_t)tz * H_ + h) * S_ + s0 + w * 32 + mt * 16 + kgrp * 4 + r]
                    = suml[mt][r];
    }
}

// ---------------------------------------------------------------------------
// attn_pv: pvp[z][t][h*64+e] = sum_{s in z half} (exp(sc[s,t]/8)/L[s])*V[s,e]
// Wave-private P partition (no QK->PV barrier); s-split x2; 1 barrier/iter
// with DMA prefetch of the next iteration. invL folded into P.
// ---------------------------------------------------------------------------
__global__ __launch_bounds__(256) void attn_pv(
    const ushort* __restrict__ QK, const ushort* __restrict__ VT,
    const float* __restrict__ statsP, ushort* __restrict__ pvp)
{
    const int h = blockIdx.y;
    const int t0 = blockIdx.x * 128;
    const int sbase = blockIdx.z * 1024;
    const int tid = threadIdx.x;
    const int lane = tid & 63;
    const int w = tid >> 6;
    const int row16 = lane & 15;
    const int kgrp = lane >> 4;

    __shared__ ushort KP[128 * 64];     // K tile, then P^T (wave-private rows)
    __shared__ ushort Qs[2][64 * 64];
    __shared__ ushort Vs[2][64 * 64];   // V^T tile [e][s]
    __shared__ float  ilL[1024];

    const int lr = lane >> 3;
    const int sw8 = ((lane & 7) ^ lr) * 8;

    // stage K tile (128 t-rows): 16 insts, 4 per wave
#pragma unroll
    for (int i = 0; i < 4; ++i) {
        const int inst = w * 4 + i;
        gload_lds16(QK + (size_t)(t0 + inst * 8 + lr) * 2048 + 1024 + h * 64 + sw8,
                    KP + inst * 512);
    }
    // stage Q/V (si=0) into buf 0
#pragma unroll
    for (int i = 0; i < 2; ++i) {
        const int inst = w * 2 + i;
        const int r = inst * 8 + lr;
        gload_lds16(QK + (size_t)(sbase + r) * 2048 + h * 64 + sw8, Qs[0] + inst * 512);
        gload_lds16(VT + (size_t)(h * 64 + r) * 2048 + sbase + sw8, Vs[0] + inst * 512);
    }
    // invL for this 1024-s chunk -> LDS
    {
        const int HS = H_ * S_;
#pragma unroll
        for (int k = 0; k < 4; ++k) {
            const int sl = tid * 4 + k;
            const int idx = h * S_ + sbase + sl;
            ilL[sl] = 1.f / (statsP[idx] + statsP[HS + idx]);
        }
    }
    __syncthreads();   // drains K + Q/V(0) DMA; publishes ilL

    // hoist own K fragments (rows w*32 .. w*32+31)
    bf16x8 kf[2][2];
#pragma unroll
    for (int nt = 0; nt < 2; ++nt) {
        const int r = w * 32 + nt * 16 + row16;
        kf[nt][0] = *(const bf16x8*)(KP + r * 64 + ((kgrp ^ (r & 7)) * 8));
        kf[nt][1] = *(const bf16x8*)(KP + r * 64 + (((kgrp + 4) ^ (r & 7)) * 8));
    }

    f32x4 acc[2][4];
#pragma unroll
    for (int i = 0; i < 2; ++i)
#pragma unroll
        for (int j = 0; j < 4; ++j) acc[i][j] = (f32x4){0.f, 0.f, 0.f, 0.f};

    for (int si = 0; si < 16; ++si) {
        if (si > 0) __syncthreads();   // drains Q/V(si) DMA; all waves past compute(si-1)
        if (si < 15) {                 // prefetch si+1 — drains one iteration later
            const int s1 = sbase + (si + 1) * 64;
            ushort* qb = Qs[(si + 1) & 1];
            ushort* vb = Vs[(si + 1) & 1];
#pragma unroll
            for (int i = 0; i < 2; ++i) {
                const int inst = w * 2 + i;
                const int r = inst * 8 + lr;
                gload_lds16(QK + (size_t)(s1 + r) * 2048 + h * 64 + sw8, qb + inst * 512);
                gload_lds16(VT + (size_t)(h * 64 + r) * 2048 + s1 + sw8, vb + inst * 512);
            }
        }
        const ushort* Qb = Qs[si & 1];
        const ushort* Vb = Vs[si & 1];

        // QK^T: m = all 4 s-tiles, n = own 2 t-tiles; P' = exp * invL -> KP
#pragma unroll
        for (int mt = 0; mt < 4; ++mt) {
            const int qr = mt * 16 + row16;
            bf16x8 qf0 = *(const bf16x8*)(Qb + qr * 64 + ((kgrp ^ (qr & 7)) * 8));
            bf16x8 qf1 = *(const bf16x8*)(Qb + qr * 64 + (((kgrp + 4) ^ (qr & 7)) * 8));
            f32x4 il4 = *(const f32x4*)(ilL + si * 64 + mt * 16 + kgrp * 4);
#pragma unroll
            for (int nt = 0; nt < 2; ++nt) {
                f32x4 sc = (f32x4){0.f, 0.f, 0.f, 0.f};
                sc = __builtin_amdgcn_mfma_f32_16x16x32_bf16(qf0, kf[nt][0], sc, 0, 0, 0);
                sc = __builtin_amdgcn_mfma_f32_16x16x32_bf16(qf1, kf[nt][1], sc, 0, 0, 0);
                ushort4 o;
                o.x = f2bf(exp8(sc[0]) * il4[0]);
                o.y = f2bf(exp8(sc[1]) * il4[1]);
                o.z = f2bf(exp8(sc[2]) * il4[2]);
                o.w = f2bf(exp8(sc[3]) * il4[3]);
                const int tl = w * 32 + nt * 16 + row16;       // wave-private row
                const int chunk = mt * 2 + (kgrp >> 1);        // s-chunk index
                *(ushort4*)(KP + tl * 64 + ((chunk ^ (tl & 7)) * 8) + (kgrp & 1) * 4) = o;
            }
        }

        // PV: A = own P^T rows (same-wave LDS dep, no barrier), B = V^T
        bf16x8 vf[4][2];
#pragma unroll
        for (int nt = 0; nt < 4; ++nt) {
            const int vr = nt * 16 + row16;
            vf[nt][0] = *(const bf16x8*)(Vb + vr * 64 + ((kgrp ^ (vr & 7)) * 8));
            vf[nt][1] = *(const bf16x8*)(Vb + vr * 64 + (((kgrp + 4) ^ (vr & 7)) * 8));
        }
#pragma unroll
        for (int mt = 0; mt < 2; ++mt) {
            const int pr = w * 32 + mt * 16 + row16;
            bf16x8 pf0 = *(const bf16x8*)(KP + pr * 64 + ((kgrp ^ (pr & 7)) * 8));
            bf16x8 pf1 = *(const bf16x8*)(KP + pr * 64 + (((kgrp + 4) ^ (pr & 7)) * 8));
#pragma unroll
            for (int nt = 0; nt < 4; ++nt) {
                acc[mt][nt] = __builtin_amdgcn_mfma_f32_16x16x32_bf16(pf0, vf[nt][0], acc[mt][nt], 0, 0, 0);
                acc[mt][nt] = __builtin_amdgcn_mfma_f32_16x16x32_bf16(pf1, vf[nt][1], acc[mt][nt], 0, 0, 0);
            }
        }
    }

    ushort* dst = pvp + (size_t)blockIdx.z * S_ * D_;
#pragma unroll
    for (int mt = 0; mt < 2; ++mt)
#pragma unroll
        for (int nt = 0; nt < 4; ++nt)
#pragma unroll
            for (int r = 0; r < 4; ++r) {
                const int t = t0 + w * 32 + mt * 16 + kgrp * 4 + r;
                const int e = nt * 16 + row16;
                dst[(size_t)t * D_ + h * 64 + e] = f2bf(acc[mt][nt][r]);
            }
}

// concat[i] = bf16(sum of 2 bf16 partials)
__global__ __launch_bounds__(256) void reduce_cat(
    const ushort* __restrict__ p, ushort* __restrict__ concat)
{
    const size_t SD = (size_t)S_ * D_;
    const size_t i = ((size_t)blockIdx.x * 256 + threadIdx.x) * 8;
    union { uint4 u; ushort s[8]; } a, b, o;
    a.u = *(const uint4*)(p + i);
    b.u = *(const uint4*)(p + SD + i);
#pragma unroll
    for (int j = 0; j < 8; ++j)
        o.s[j] = f2bf(bf2f(a.s[j]) + bf2f(b.s[j]));
    *(uint4*)(concat + i) = o.u;
}

// ---------------------------------------------------------------------------
extern "C" void kernel_launch(void* const* d_in, const int* in_sizes, int n_in,
                              void* d_out, int out_size, void* d_ws,
                              size_t ws_size, hipStream_t stream)
{
    const float* x  = (const float*)d_in[0];
    const float* Wq = (const float*)d_in[1];
    const float* bq = (const float*)d_in[2];
    const float* Wk = (const float*)d_in[3];
    const float* bk = (const float*)d_in[4];
    const float* Wv = (const float*)d_in[5];
    const float* bv = (const float*)d_in[6];
    const float* Wp = (const float*)d_in[7];
    const float* bp = (const float*)d_in[8];
    const float* W1 = (const float*)d_in[9];
    const float* b1 = (const float*)d_in[10];
    const float* W2 = (const float*)d_in[11];
    const float* b2 = (const float*)d_in[12];
    float* out = (float*)d_out;

    // Workspace (MB offsets); phase-disjoint aliasing:
    constexpr size_t MB = 1u << 20;
    char* base = (char*)d_ws;
    ushort* BT2    = (ushort*)(base +  0 * MB);  // 8   pack -> FF2
    ushort* BT1    = (ushort*)(base +  8 * MB);  // 8   pack -> FF1
    ushort* BTp    = (ushort*)(base + 16 * MB);  // 2   pack -> proj
    ushort* xb     = (ushort*)(base + 18 * MB);  // 4   pack -> QKV
    ushort* concat = (ushort*)(base + 18 * MB);  // 4   reduce_cat -> proj (over xb)
    ushort* BTqkv  = (ushort*)(base + 22 * MB);  // 6   pack -> QKV
    ushort* projb  = (ushort*)(base + 22 * MB);  // 4   proj -> FF1 (over BTqkv)
    ushort* QKcat  = (ushort*)(base + 28 * MB);  // 8   QKV -> pv
    ushort* VTg    = (ushort*)(base + 36 * MB);  // 4   QKV -> pv
    ushort* pvp    = (ushort*)(base + 40 * MB);  // 8   pv -> reduce_cat (x2 bf16)
    ushort* hidden = (ushort*)(base + 28 * MB);  // 16  FF1 -> FF2 (over QKcat+VTg)
    ushort* ff2p   = (ushort*)(base + 44 * MB);  // 16  FF2 -> reduce4 (4x bf16, over pvp tail)
    float*  biascat= (float*) (base + 60 * MB);
    float*  statsP = biascat + 4096;             // 2 * H*S fp32

    // 1) pack (one launch)
    pack_all<<<dim3(5132), 256, 0, stream>>>(
        x, Wq, Wk, Wv, Wp, W1, W2, bq, bk, bv,
        xb, BTqkv, BTp, BT1, BT2, biascat);

    // 2) fused QKV projection -> QKcat [S][2048] + V^T [1024][S]
    gemm_mfma<128, 128, 2, 2, 1, 0, 3>
        <<<dim3(3072 / 128, S_ / 128, 1), 256, 0, stream>>>(
            xb, BTqkv, biascat, QKcat, VTg, S_, 3072, D_);

    // 3) softmax denominators (t-split x2)
    attn_stats<<<dim3(S_ / 128, H_, 2), 256, 0, stream>>>(QKcat, statsP);

    // 4) PV (s-split x2, bf16 partials; invL folded in)
    attn_pv<<<dim3(S_ / 128, H_, 2), 256, 0, stream>>>(QKcat, VTg, statsP, pvp);

    // 5) sum partials -> concat
    reduce_cat<<<dim3(S_ * D_ / 2048), 256, 0, stream>>>(pvp, concat);

    // 6) output projection: single pass, 64x64 tiles -> 512 blocks, bf16+bias
    gemm_mfma<64, 64, 2, 2, 1, 0, 1>
        <<<dim3(D_ / 64, S_ / 64, 1), 256, 0, stream>>>(
            concat, BTp, bp, projb, nullptr, S_, D_, D_);

    // 7) FF1 (+relu)
    gemm_mfma<128, 128, 2, 2, 1, 1, 1>
        <<<dim3(FF_ / 128, S_ / 128, 1), 256, 0, stream>>>(
            projb, BT1, b1, hidden, nullptr, S_, FF_, D_);

    // 8) FF2 split-K=4, bf16 partials (single 16 MB region)
    gemm_mfma<128, 128, 2, 2, 4, 0, 4>
        <<<dim3(D_ / 128, S_ / 128, 4), 256, 0, stream>>>(
            hidden, BT2, nullptr, ff2p, nullptr, S_, D_, FF_);

    // 9) reduce + bias -> out
    reduce4_bias_b<<<dim3(S_ * D_ / 2048), 256, 0, stream>>>(
        ff2p, b2, out, S_ * D_, D_);
}